// Round 6
// baseline (3739.570 us; speedup 1.0000x reference)
//
#include <hip/hip_runtime.h>

#define BATCH 2
#define NV 40000
#define NPTS 32
#define GXX 750
#define GYY 750
#define HWSZ (GXX*GYY)          // 562500
#define HIDC 64
#define OUTCH 128
#define NROWS (BATCH*NV*NPTS)   // 2560000
#define NBHW (BATCH*HWSZ)       // 1125000
#define EPSB 1e-5f

// workspace float offsets
#define OFF_CENTER 0            // B*V*3 = 240000 floats
#define OFF_STATS1 240000       // 128
#define OFF_AC1    240128       // 128
#define OFF_STATS2 240256       // 128
#define OFF_AC2    240384       // 128
#define OFF_SC1    240512       // 128
#define OFF_ACC1   240640       // 128
#define OFF_SC2    240768       // 128
#define OFF_ACC2   240896       // 128
#define OFF_SC3    241024       // 256
#define OFF_ACC3   241280       // 256
#define OFF_STATS_END 241536
#define OFF_WB1    241536       // 36864 ushort = 18432 floats
#define OFF_WB2    259968       // 36864 ushort
#define OFF_WB3    278400       // 73728 ushort = 36864 floats -> ends 315264
#define OFF_BEV    327680       // NHWC bf16: B*HW*64 ushort = 72M us = 36M floats
#define OFF_MID    36327680     // NHWC bf16: 36M floats -> ends 72,327,680 (~289MB)

typedef __attribute__((ext_vector_type(8))) short bfrag8;   // 8 bf16 in 4 VGPRs
typedef __attribute__((ext_vector_type(4))) float f32x4;

__device__ __forceinline__ ushort f2bf(float f) {
    union { float f; unsigned u; } v; v.f = f;
    unsigned u = v.u;
    return (ushort)((u + 0x7FFFu + ((u >> 16) & 1u)) >> 16);   // RNE
}

// ---------------- pillar centers ----------------
__global__ __launch_bounds__(256) void k_center(const float* __restrict__ vox,
                                                const int* __restrict__ npts,
                                                float* __restrict__ center) {
    int i = blockIdx.x * 256 + threadIdx.x;
    if (i >= BATCH * NV) return;
    int np = npts[i];
    if (np < 0) np = 0;
    if (np > NPTS) np = NPTS;
    const float* vp = vox + (size_t)i * (NPTS * 4);
    float sx = 0.f, sy = 0.f, sz = 0.f;
    for (int p = 0; p < np; ++p) {
        sx += vp[p * 4 + 0];
        sy += vp[p * 4 + 1];
        sz += vp[p * 4 + 2];
    }
    float cnt = np > 0 ? (float)np : 1.0f;
    center[i * 3 + 0] = sx / cnt;
    center[i * 3 + 1] = sy / cnt;
    center[i * 3 + 2] = sz / cnt;
}

// ---------------- FC1 stats ----------------
__global__ __launch_bounds__(256) void k_fc1_stats(const float* __restrict__ vox,
                                                   const float* __restrict__ center,
                                                   const float* __restrict__ W1,
                                                   const float* __restrict__ b1,
                                                   float* __restrict__ stats) {
    __shared__ float sAug[64][12];
    __shared__ float red[2][4][64];
    const int t = threadIdx.x;
    const int c = t & 63, g = t >> 6;
    float w1c[10];
#pragma unroll
    for (int k = 0; k < 10; ++k) w1c[k] = W1[k * 64 + c];
    const float b1c = b1[c];
    float s0 = 0.f, s1 = 0.f;
    for (int tile = blockIdx.x; tile < NROWS / 64; tile += gridDim.x) {
        __syncthreads();
        if (t < 64) {
            int row = tile * 64 + t;
            int pil = row >> 5;
            float4 v = *(const float4*)(vox + (size_t)row * 4);
            float cx = center[pil * 3 + 0];
            float cy = center[pil * 3 + 1];
            float cz = center[pil * 3 + 2];
            sAug[t][0] = v.x; sAug[t][1] = v.y; sAug[t][2] = v.z; sAug[t][3] = v.w;
            sAug[t][4] = v.x - cx; sAug[t][5] = v.y - cy; sAug[t][6] = v.z - cz;
            sAug[t][7] = v.x - cx; sAug[t][8] = v.y - cy; sAug[t][9] = v.z - cz;
        }
        __syncthreads();
        for (int r = g; r < 64; r += 4) {
            float y = b1c;
#pragma unroll
            for (int k = 0; k < 10; ++k) y += sAug[r][k] * w1c[k];
            s0 += y;
            s1 += y * y;
        }
    }
    __syncthreads();
    red[0][g][c] = s0;
    red[1][g][c] = s1;
    __syncthreads();
    if (t < 64) {
        float a = red[0][0][t] + red[0][1][t] + red[0][2][t] + red[0][3][t];
        float b = red[1][0][t] + red[1][1][t] + red[1][2][t] + red[1][3][t];
        atomicAdd(&stats[t], a);
        atomicAdd(&stats[64 + t], b);
    }
}

// ---------------- finalize BN ----------------
__global__ void k_finalize(const float* __restrict__ stats,
                           const float* __restrict__ gamma,
                           const float* __restrict__ beta,
                           float* __restrict__ ac, int nch, float invN) {
    int c = blockIdx.x * blockDim.x + threadIdx.x;
    if (c >= nch) return;
    float m = stats[c] * invN;
    float v = stats[nch + c] * invN - m * m;
    if (v < 0.f) v = 0.f;
    float a = gamma[c] * rsqrtf(v + EPSB);
    ac[c] = a;
    ac[nch + c] = beta[c] - m * a;
}

// ---------------- FC2 stats ----------------
__global__ __launch_bounds__(256) void k_fc2_stats(const float* __restrict__ vox,
                                                   const float* __restrict__ center,
                                                   const float* __restrict__ W1,
                                                   const float* __restrict__ b1,
                                                   const float* __restrict__ ac1,
                                                   const float* __restrict__ W2,
                                                   const float* __restrict__ b2,
                                                   float* __restrict__ stats) {
    __shared__ float sAug[64][12];
    __shared__ float sH[64][68];
    __shared__ float red[2][4][64];
    const int t = threadIdx.x;
    const int c = t & 63, g = t >> 6;
    float w1c[10];
#pragma unroll
    for (int k = 0; k < 10; ++k) w1c[k] = W1[k * 64 + c];
    float w2c[64];
#pragma unroll
    for (int k = 0; k < 64; ++k) w2c[k] = W2[k * 64 + c];
    const float b1c = b1[c];
    const float a1 = ac1[c], c1 = ac1[64 + c];
    const float b2c = b2[c];
    float s0 = 0.f, s1 = 0.f;
    for (int tile = blockIdx.x; tile < NROWS / 64; tile += gridDim.x) {
        __syncthreads();
        if (t < 64) {
            int row = tile * 64 + t;
            int pil = row >> 5;
            float4 v = *(const float4*)(vox + (size_t)row * 4);
            float cx = center[pil * 3 + 0];
            float cy = center[pil * 3 + 1];
            float cz = center[pil * 3 + 2];
            sAug[t][0] = v.x; sAug[t][1] = v.y; sAug[t][2] = v.z; sAug[t][3] = v.w;
            sAug[t][4] = v.x - cx; sAug[t][5] = v.y - cy; sAug[t][6] = v.z - cz;
            sAug[t][7] = v.x - cx; sAug[t][8] = v.y - cy; sAug[t][9] = v.z - cz;
        }
        __syncthreads();
        for (int r = g; r < 64; r += 4) {
            float y = b1c;
#pragma unroll
            for (int k = 0; k < 10; ++k) y += sAug[r][k] * w1c[k];
            y = a1 * y + c1;
            sH[r][c] = y > 0.f ? y : 0.f;
        }
        __syncthreads();
        for (int r = g; r < 64; r += 4) {
            float y = b2c;
#pragma unroll
            for (int k = 0; k < 64; k += 4) {
                float4 h = *(const float4*)&sH[r][k];
                y += h.x * w2c[k] + h.y * w2c[k + 1] + h.z * w2c[k + 2] + h.w * w2c[k + 3];
            }
            s0 += y;
            s1 += y * y;
        }
    }
    __syncthreads();
    red[0][g][c] = s0;
    red[1][g][c] = s1;
    __syncthreads();
    if (t < 64) {
        float a = red[0][0][t] + red[0][1][t] + red[0][2][t] + red[0][3][t];
        float b = red[1][0][t] + red[1][1][t] + red[1][2][t] + red[1][3][t];
        atomicAdd(&stats[t], a);
        atomicAdd(&stats[64 + t], b);
    }
}

// ---------------- final MLP pass + masked max + scatter into NHWC bf16 bev ----------------
__global__ __launch_bounds__(256) void k_pillar(const float* __restrict__ vox,
                                                const int* __restrict__ npts,
                                                const int* __restrict__ coords,
                                                const float* __restrict__ center,
                                                const float* __restrict__ W1,
                                                const float* __restrict__ b1,
                                                const float* __restrict__ ac1,
                                                const float* __restrict__ W2,
                                                const float* __restrict__ b2,
                                                const float* __restrict__ ac2,
                                                ushort* __restrict__ bev) {
    __shared__ float sAug[32][12];
    __shared__ float sH[32][68];
    __shared__ float red[4][64];
    const int t = threadIdx.x;
    const int c = t & 63, g = t >> 6;
    float w1c[10];
#pragma unroll
    for (int k = 0; k < 10; ++k) w1c[k] = W1[k * 64 + c];
    float w2c[64];
#pragma unroll
    for (int k = 0; k < 64; ++k) w2c[k] = W2[k * 64 + c];
    const float b1c = b1[c];
    const float a1 = ac1[c], c1 = ac1[64 + c];
    const float b2c = b2[c];
    const float a2 = ac2[c], c2 = ac2[64 + c];

    for (int pil = blockIdx.x; pil < BATCH * NV; pil += gridDim.x) {
        __syncthreads();
        int np = npts[pil];
        if (np < 0) np = 0;
        if (np > NPTS) np = NPTS;
        if (t < 32) {
            int row = pil * 32 + t;
            float4 v = *(const float4*)(vox + (size_t)row * 4);
            float cx = center[pil * 3 + 0];
            float cy = center[pil * 3 + 1];
            float cz = center[pil * 3 + 2];
            sAug[t][0] = v.x; sAug[t][1] = v.y; sAug[t][2] = v.z; sAug[t][3] = v.w;
            sAug[t][4] = v.x - cx; sAug[t][5] = v.y - cy; sAug[t][6] = v.z - cz;
            sAug[t][7] = v.x - cx; sAug[t][8] = v.y - cy; sAug[t][9] = v.z - cz;
        }
        __syncthreads();
        for (int p = g; p < np; p += 4) {
            float y = b1c;
#pragma unroll
            for (int k = 0; k < 10; ++k) y += sAug[p][k] * w1c[k];
            y = a1 * y + c1;
            sH[p][c] = y > 0.f ? y : 0.f;
        }
        __syncthreads();
        float mx = 0.f;
        for (int p = g; p < np; p += 4) {
            float y = b2c;
#pragma unroll
            for (int k = 0; k < 64; k += 4) {
                float4 h = *(const float4*)&sH[p][k];
                y += h.x * w2c[k] + h.y * w2c[k + 1] + h.z * w2c[k + 2] + h.w * w2c[k + 3];
            }
            y = a2 * y + c2;
            if (y > mx) mx = y;
        }
        red[g][c] = mx;
        __syncthreads();
        if (t < 64) {
            float m0 = red[0][t] > red[1][t] ? red[0][t] : red[1][t];
            float m1 = red[2][t] > red[3][t] ? red[2][t] : red[3][t];
            float m = m0 > m1 ? m0 : m1;
            int x = coords[pil * 3 + 0];
            int y = coords[pil * 3 + 1];
            if (x >= 0 && x < GXX && y >= 0 && y < GYY) {
                int b = pil / NV;
                bev[((size_t)((b * GYY + y) * GXX + x)) * 64 + t] = f2bf(m);
            }
        }
    }
}

// ---------------- weight convert: W[OC][64][3][3] fp32 -> Wb[tap][OC][64 ic] bf16 ----------------
__global__ __launch_bounds__(256) void k_wcvt(const float* __restrict__ src,
                                              ushort* __restrict__ dst, int OC) {
    int idx = blockIdx.x * 256 + threadIdx.x;
    if (idx >= OC * 64 * 9) return;
    int oc = idx / 576;
    int rem = idx - oc * 576;
    int ic = rem / 9;
    int tp = rem - ic * 9;
    dst[((size_t)(tp * OC + oc)) * 64 + ic] = f2bf(src[idx]);
}

// ---------------- MFMA 3x3 SAME conv, NHWC bf16 in, weights in VGPRs ----------------
// 16x16 px tile, 4 waves (wave = 4 y-rows, all 64 oc of slab). Two ic-32 passes:
// per pass, w[9][4] bfrag8 preloaded to regs (144 VGPR), X half-tile in LDS.
// LDS X rows padded to 80B (20 dwords): start bank group (5*pix + chunk) % 8
// is bijective in pix -> conflict-free b128 reads/writes (2-way aliasing only).
#define ICP2 40            // ushorts per pixel per pass (32 ch + 8 pad)
__global__ __launch_bounds__(256, 2) void k_conv_mfma(const ushort* __restrict__ in,
                                                      const ushort* __restrict__ Wb,
                                                      const float* __restrict__ bias,
                                                      const float* __restrict__ acIn,
                                                      int useAffine,
                                                      float* __restrict__ outF,
                                                      ushort* __restrict__ outH,
                                                      int N,
                                                      float* __restrict__ stats) {
    __shared__ ushort sX[18 * 18 * ICP2];      // 25920 B
    __shared__ float sStat[2][4][64];           // 2 KB
    const int t = threadIdx.x;
    const int wid = t >> 6, l = t & 63;
    const int hi = l >> 4, lr = l & 15;
    const int tilex = blockIdx.x % 47, tiley = blockIdx.x / 47;
    const int x0 = tilex * 16, y0 = tiley * 16;
    const int ocb = blockIdx.y * 64;
    const int b = blockIdx.z;
    const int cch = t & 3;       // staging chunk (8 ch) within pass
    const int px0 = t >> 2;      // staging start pixel

    f32x4 acc[4][4];
#pragma unroll
    for (int m = 0; m < 4; ++m)
#pragma unroll
        for (int n = 0; n < 4; ++n) acc[m][n] = (f32x4){0.f, 0.f, 0.f, 0.f};

#pragma unroll
    for (int pass = 0; pass < 2; ++pass) {
        __syncthreads();   // prior pass's reads done before overwrite
        // ---- preload W for this pass into registers (36 x 16B, from L2) ----
        bfrag8 w[9][4];
#pragma unroll
        for (int tp = 0; tp < 9; ++tp)
#pragma unroll
            for (int n = 0; n < 4; ++n)
                w[tp][n] = *(const bfrag8*)(Wb + ((size_t)(tp * N + ocb + n * 16 + lr)) * 64
                                            + pass * 32 + hi * 8);
        // ---- affine coefficients for this thread's 8-ch chunk ----
        float aA[8], aC[8];
        if (useAffine) {
#pragma unroll
            for (int i = 0; i < 8; ++i) {
                aA[i] = acIn[pass * 32 + cch * 8 + i];
                aC[i] = acIn[64 + pass * 32 + cch * 8 + i];
            }
        }
        // ---- stage X half-tile (18x18 px, 32 ch) ----
        for (int pix = px0; pix < 324; pix += 64) {
            int r = pix / 18, cpx = pix - r * 18;
            int gy = y0 + r - 1, gx = x0 + cpx - 1;
            uint4 v = {0u, 0u, 0u, 0u};
            if (gy >= 0 && gy < GYY && gx >= 0 && gx < GXX) {
                v = *(const uint4*)(in + ((size_t)((b * GYY + gy) * GXX + gx)) * 64
                                    + pass * 32 + cch * 8);
                if (useAffine) {
                    uint uu[4] = {v.x, v.y, v.z, v.w};
#pragma unroll
                    for (int p = 0; p < 4; ++p) {
                        float f0 = __uint_as_float(uu[p] << 16);
                        float f1 = __uint_as_float(uu[p] & 0xFFFF0000u);
                        f0 = fmaxf(fmaf(aA[p * 2], f0, aC[p * 2]), 0.f);
                        f1 = fmaxf(fmaf(aA[p * 2 + 1], f1, aC[p * 2 + 1]), 0.f);
                        uu[p] = (uint)f2bf(f0) | ((uint)f2bf(f1) << 16);
                    }
                    v.x = uu[0]; v.y = uu[1]; v.z = uu[2]; v.w = uu[3];
                }
            }
            *(uint4*)(&sX[pix * ICP2 + cch * 8]) = v;
        }
        __syncthreads();
        // ---- compute: 9 taps, pure LDS + MFMA ----
        const int yb = wid * 4;
#pragma unroll
        for (int tp = 0; tp < 9; ++tp) {
            const int dy = tp / 3 - 1, dx = tp % 3 - 1;
#pragma unroll
            for (int m = 0; m < 4; ++m) {
                int pix = (yb + m + 1 + dy) * 18 + (lr + 1 + dx);
                bfrag8 a = *(const bfrag8*)(&sX[pix * ICP2 + hi * 8]);
#pragma unroll
                for (int n = 0; n < 4; ++n)
                    acc[m][n] = __builtin_amdgcn_mfma_f32_16x16x32_bf16(a, w[tp][n], acc[m][n], 0, 0, 0);
            }
        }
    }

    // ---- epilogue: bias, store pre-BN, stats ----
    float ssum[4] = {0.f, 0.f, 0.f, 0.f}, ssq[4] = {0.f, 0.f, 0.f, 0.f};
#pragma unroll
    for (int n = 0; n < 4; ++n) {
        const int oc = ocb + n * 16 + lr;
        const float bo = bias[oc];
#pragma unroll
        for (int m = 0; m < 4; ++m) {
            int y = y0 + wid * 4 + m;
            if (y < GYY) {
#pragma unroll
                for (int j = 0; j < 4; ++j) {
                    int x = x0 + hi * 4 + j;
                    if (x < GXX) {
                        float v = acc[m][n][j] + bo;
                        if (outH) outH[((size_t)((b * GYY + y) * GXX + x)) * 64 + oc] = f2bf(v);
                        else outF[((size_t)(b * N + oc)) * HWSZ + (size_t)y * GXX + x] = v;
                        ssum[n] += v;
                        ssq[n] += v * v;
                    }
                }
            }
        }
    }
#pragma unroll
    for (int n = 0; n < 4; ++n) {
        ssum[n] += __shfl_xor(ssum[n], 16);
        ssum[n] += __shfl_xor(ssum[n], 32);
        ssq[n] += __shfl_xor(ssq[n], 16);
        ssq[n] += __shfl_xor(ssq[n], 32);
    }
    if (l < 16) {
#pragma unroll
        for (int n = 0; n < 4; ++n) {
            sStat[0][wid][n * 16 + l] = ssum[n];
            sStat[1][wid][n * 16 + l] = ssq[n];
        }
    }
    __syncthreads();
    if (t < 64) {
        float s = sStat[0][0][t] + sStat[0][1][t] + sStat[0][2][t] + sStat[0][3][t];
        float q = sStat[1][0][t] + sStat[1][1][t] + sStat[1][2][t] + sStat[1][3][t];
        atomicAdd(&stats[ocb + t], s);
        atomicAdd(&stats[N + ocb + t], q);
    }
}

// ---------------- in-place BN affine + relu on final output ----------------
__global__ __launch_bounds__(256) void k_bnrelu(float* __restrict__ x,
                                                const float* __restrict__ ac, int nch) {
    const int hw4 = HWSZ / 4;  // 140625
    size_t total = (size_t)BATCH * nch * hw4;
    size_t stride = (size_t)gridDim.x * 256;
    for (size_t idx = (size_t)blockIdx.x * 256 + threadIdx.x; idx < total; idx += stride) {
        int c = (int)((idx / hw4) % nch);
        float a = ac[c], cc = ac[nch + c];
        float4 v = ((float4*)x)[idx];
        v.x = fmaxf(a * v.x + cc, 0.f);
        v.y = fmaxf(a * v.y + cc, 0.f);
        v.z = fmaxf(a * v.z + cc, 0.f);
        v.w = fmaxf(a * v.w + cc, 0.f);
        ((float4*)x)[idx] = v;
    }
}

extern "C" void kernel_launch(void* const* d_in, const int* in_sizes, int n_in,
                              void* d_out, int out_size, void* d_ws, size_t ws_size,
                              hipStream_t stream) {
    const float* voxels = (const float*)d_in[0];
    const int* num_points = (const int*)d_in[1];
    const int* coords = (const int*)d_in[2];
    const float* W1 = (const float*)d_in[3];
    const float* b1 = (const float*)d_in[4];
    const float* g1 = (const float*)d_in[5];
    const float* be1 = (const float*)d_in[6];
    const float* W2 = (const float*)d_in[7];
    const float* b2 = (const float*)d_in[8];
    const float* g2 = (const float*)d_in[9];
    const float* be2 = (const float*)d_in[10];
    const float* Wc1 = (const float*)d_in[11];
    const float* bc1 = (const float*)d_in[12];
    const float* gc1 = (const float*)d_in[13];
    const float* bec1 = (const float*)d_in[14];
    const float* Wc2 = (const float*)d_in[15];
    const float* bc2 = (const float*)d_in[16];
    const float* gc2 = (const float*)d_in[17];
    const float* bec2 = (const float*)d_in[18];
    const float* Wc3 = (const float*)d_in[19];
    const float* bc3 = (const float*)d_in[20];
    const float* gc3 = (const float*)d_in[21];
    const float* bec3 = (const float*)d_in[22];

    float* ws = (float*)d_ws;
    float* center = ws + OFF_CENTER;
    float* stats1 = ws + OFF_STATS1;
    float* ac1 = ws + OFF_AC1;
    float* stats2 = ws + OFF_STATS2;
    float* ac2 = ws + OFF_AC2;
    float* sC1 = ws + OFF_SC1;
    float* acC1 = ws + OFF_ACC1;
    float* sC2 = ws + OFF_SC2;
    float* acC2 = ws + OFF_ACC2;
    float* sC3 = ws + OFF_SC3;
    float* acC3 = ws + OFF_ACC3;
    ushort* Wb1 = (ushort*)(ws + OFF_WB1);
    ushort* Wb2 = (ushort*)(ws + OFF_WB2);
    ushort* Wb3 = (ushort*)(ws + OFF_WB3);
    ushort* bev = (ushort*)(ws + OFF_BEV);   // NHWC bf16
    ushort* mid = (ushort*)(ws + OFF_MID);   // NHWC bf16
    float* outf = (float*)d_out;

    // zero stats block and NHWC bev grid (bf16 zero = 0x0000)
    hipMemsetAsync((char*)d_ws + OFF_STATS1 * sizeof(float), 0,
                   (OFF_STATS_END - OFF_STATS1) * sizeof(float), stream);
    hipMemsetAsync((char*)d_ws + OFF_BEV * sizeof(float), 0,
                   (size_t)BATCH * HWSZ * 64 * sizeof(ushort), stream);

    // weight conversion to bf16 (tap-major)
    k_wcvt<<<144, 256, 0, stream>>>(Wc1, Wb1, 64);
    k_wcvt<<<144, 256, 0, stream>>>(Wc2, Wb2, 64);
    k_wcvt<<<288, 256, 0, stream>>>(Wc3, Wb3, 128);

    // pillar centers
    k_center<<<(BATCH * NV + 255) / 256, 256, 0, stream>>>(voxels, num_points, center);

    // FC1 stats -> affine
    k_fc1_stats<<<1024, 256, 0, stream>>>(voxels, center, W1, b1, stats1);
    k_finalize<<<1, 64, 0, stream>>>(stats1, g1, be1, ac1, 64, 1.0f / NROWS);

    // FC2 stats -> affine
    k_fc2_stats<<<1024, 256, 0, stream>>>(voxels, center, W1, b1, ac1, W2, b2, stats2);
    k_finalize<<<1, 64, 0, stream>>>(stats2, g2, be2, ac2, 64, 1.0f / NROWS);

    // final MLP + max + scatter (NHWC bf16)
    k_pillar<<<4096, 256, 0, stream>>>(voxels, num_points, coords, center,
                                       W1, b1, ac1, W2, b2, ac2, bev);

    const int NT = 47 * 47;
    // conv1: bev(NHWC bf16) -> mid(NHWC bf16 pre-BN), stats
    {
        dim3 grid(NT, 1, BATCH);
        k_conv_mfma<<<grid, 256, 0, stream>>>(bev, Wb1, bc1, nullptr, 0,
                                              nullptr, mid, 64, sC1);
        k_finalize<<<1, 64, 0, stream>>>(sC1, gc1, bec1, acC1, 64, 1.0f / NBHW);
    }
    // conv2: mid (affine+relu on load) -> bev(NHWC bf16 pre-BN), stats
    {
        dim3 grid(NT, 1, BATCH);
        k_conv_mfma<<<grid, 256, 0, stream>>>(mid, Wb2, bc2, acC1, 1,
                                              nullptr, bev, 64, sC2);
        k_finalize<<<1, 64, 0, stream>>>(sC2, gc2, bec2, acC2, 64, 1.0f / NBHW);
    }
    // conv3: bev (affine+relu on load) -> d_out fp32 NCHW pre-BN, stats
    {
        dim3 grid(NT, 2, BATCH);
        k_conv_mfma<<<grid, 256, 0, stream>>>(bev, Wb3, bc3, acC2, 1,
                                              outf, nullptr, 128, sC3);
        k_finalize<<<1, 128, 0, stream>>>(sC3, gc3, bec3, acC3, 128, 1.0f / NBHW);
    }
    // final BN + relu in place on d_out
    k_bnrelu<<<4096, 256, 0, stream>>>(outf, acC3, 128);
}

// Round 9
// 2782.556 us; speedup vs baseline: 1.3439x; 1.3439x over previous
//
#include <hip/hip_runtime.h>

#define BATCH 2
#define NV 40000
#define NPTS 32
#define GXX 750
#define GYY 750
#define HWSZ (GXX*GYY)          // 562500
#define HIDC 64
#define OUTCH 128
#define NROWS (BATCH*NV*NPTS)   // 2560000
#define NBHW (BATCH*HWSZ)       // 1125000
#define EPSB 1e-5f

// workspace float offsets
#define OFF_CENTER 0            // B*V*3 = 240000 floats
#define OFF_STATS1 240000       // 128
#define OFF_AC1    240128       // 128
#define OFF_STATS2 240256       // 128
#define OFF_AC2    240384       // 128
#define OFF_SC1    240512       // 128
#define OFF_ACC1   240640       // 128
#define OFF_SC2    240768       // 128
#define OFF_ACC2   240896       // 128
#define OFF_SC3    241024       // 256
#define OFF_ACC3   241280       // 256
#define OFF_STATS_END 241536
#define OFF_WB1    241536       // 36864 ushort = 18432 floats
#define OFF_WB2    259968       // 36864 ushort
#define OFF_WB3    278400       // 73728 ushort = 36864 floats -> ends 315264
#define OFF_BEV    327680       // NHWC bf16: B*HW*64 ushort = 72M us = 36M floats
#define OFF_MID    36327680     // NHWC bf16: 36M floats -> ends 72,327,680 (~289MB)

typedef __attribute__((ext_vector_type(8))) short bfrag8;   // 8 bf16 in 4 VGPRs
typedef __attribute__((ext_vector_type(4))) float f32x4;

__device__ __forceinline__ ushort f2bf(float f) {
    union { float f; unsigned u; } v; v.f = f;
    unsigned u = v.u;
    return (ushort)((u + 0x7FFFu + ((u >> 16) & 1u)) >> 16);   // RNE
}

// ---------------- pillar centers ----------------
__global__ __launch_bounds__(256) void k_center(const float* __restrict__ vox,
                                                const int* __restrict__ npts,
                                                float* __restrict__ center) {
    int i = blockIdx.x * 256 + threadIdx.x;
    if (i >= BATCH * NV) return;
    int np = npts[i];
    if (np < 0) np = 0;
    if (np > NPTS) np = NPTS;
    const float* vp = vox + (size_t)i * (NPTS * 4);
    float sx = 0.f, sy = 0.f, sz = 0.f;
    for (int p = 0; p < np; ++p) {
        sx += vp[p * 4 + 0];
        sy += vp[p * 4 + 1];
        sz += vp[p * 4 + 2];
    }
    float cnt = np > 0 ? (float)np : 1.0f;
    center[i * 3 + 0] = sx / cnt;
    center[i * 3 + 1] = sy / cnt;
    center[i * 3 + 2] = sz / cnt;
}

// ---------------- FC1 stats ----------------
__global__ __launch_bounds__(256) void k_fc1_stats(const float* __restrict__ vox,
                                                   const float* __restrict__ center,
                                                   const float* __restrict__ W1,
                                                   const float* __restrict__ b1,
                                                   float* __restrict__ stats) {
    __shared__ float sAug[64][12];
    __shared__ float red[2][4][64];
    const int t = threadIdx.x;
    const int c = t & 63, g = t >> 6;
    float w1c[10];
#pragma unroll
    for (int k = 0; k < 10; ++k) w1c[k] = W1[k * 64 + c];
    const float b1c = b1[c];
    float s0 = 0.f, s1 = 0.f;
    for (int tile = blockIdx.x; tile < NROWS / 64; tile += gridDim.x) {
        __syncthreads();
        if (t < 64) {
            int row = tile * 64 + t;
            int pil = row >> 5;
            float4 v = *(const float4*)(vox + (size_t)row * 4);
            float cx = center[pil * 3 + 0];
            float cy = center[pil * 3 + 1];
            float cz = center[pil * 3 + 2];
            sAug[t][0] = v.x; sAug[t][1] = v.y; sAug[t][2] = v.z; sAug[t][3] = v.w;
            sAug[t][4] = v.x - cx; sAug[t][5] = v.y - cy; sAug[t][6] = v.z - cz;
            sAug[t][7] = v.x - cx; sAug[t][8] = v.y - cy; sAug[t][9] = v.z - cz;
        }
        __syncthreads();
        for (int r = g; r < 64; r += 4) {
            float y = b1c;
#pragma unroll
            for (int k = 0; k < 10; ++k) y += sAug[r][k] * w1c[k];
            s0 += y;
            s1 += y * y;
        }
    }
    __syncthreads();
    red[0][g][c] = s0;
    red[1][g][c] = s1;
    __syncthreads();
    if (t < 64) {
        float a = red[0][0][t] + red[0][1][t] + red[0][2][t] + red[0][3][t];
        float b = red[1][0][t] + red[1][1][t] + red[1][2][t] + red[1][3][t];
        atomicAdd(&stats[t], a);
        atomicAdd(&stats[64 + t], b);
    }
}

// ---------------- finalize BN ----------------
__global__ void k_finalize(const float* __restrict__ stats,
                           const float* __restrict__ gamma,
                           const float* __restrict__ beta,
                           float* __restrict__ ac, int nch, float invN) {
    int c = blockIdx.x * blockDim.x + threadIdx.x;
    if (c >= nch) return;
    float m = stats[c] * invN;
    float v = stats[nch + c] * invN - m * m;
    if (v < 0.f) v = 0.f;
    float a = gamma[c] * rsqrtf(v + EPSB);
    ac[c] = a;
    ac[nch + c] = beta[c] - m * a;
}

// ---------------- FC2 stats ----------------
__global__ __launch_bounds__(256) void k_fc2_stats(const float* __restrict__ vox,
                                                   const float* __restrict__ center,
                                                   const float* __restrict__ W1,
                                                   const float* __restrict__ b1,
                                                   const float* __restrict__ ac1,
                                                   const float* __restrict__ W2,
                                                   const float* __restrict__ b2,
                                                   float* __restrict__ stats) {
    __shared__ float sAug[64][12];
    __shared__ float sH[64][68];
    __shared__ float red[2][4][64];
    const int t = threadIdx.x;
    const int c = t & 63, g = t >> 6;
    float w1c[10];
#pragma unroll
    for (int k = 0; k < 10; ++k) w1c[k] = W1[k * 64 + c];
    float w2c[64];
#pragma unroll
    for (int k = 0; k < 64; ++k) w2c[k] = W2[k * 64 + c];
    const float b1c = b1[c];
    const float a1 = ac1[c], c1 = ac1[64 + c];
    const float b2c = b2[c];
    float s0 = 0.f, s1 = 0.f;
    for (int tile = blockIdx.x; tile < NROWS / 64; tile += gridDim.x) {
        __syncthreads();
        if (t < 64) {
            int row = tile * 64 + t;
            int pil = row >> 5;
            float4 v = *(const float4*)(vox + (size_t)row * 4);
            float cx = center[pil * 3 + 0];
            float cy = center[pil * 3 + 1];
            float cz = center[pil * 3 + 2];
            sAug[t][0] = v.x; sAug[t][1] = v.y; sAug[t][2] = v.z; sAug[t][3] = v.w;
            sAug[t][4] = v.x - cx; sAug[t][5] = v.y - cy; sAug[t][6] = v.z - cz;
            sAug[t][7] = v.x - cx; sAug[t][8] = v.y - cy; sAug[t][9] = v.z - cz;
        }
        __syncthreads();
        for (int r = g; r < 64; r += 4) {
            float y = b1c;
#pragma unroll
            for (int k = 0; k < 10; ++k) y += sAug[r][k] * w1c[k];
            y = a1 * y + c1;
            sH[r][c] = y > 0.f ? y : 0.f;
        }
        __syncthreads();
        for (int r = g; r < 64; r += 4) {
            float y = b2c;
#pragma unroll
            for (int k = 0; k < 64; k += 4) {
                float4 h = *(const float4*)&sH[r][k];
                y += h.x * w2c[k] + h.y * w2c[k + 1] + h.z * w2c[k + 2] + h.w * w2c[k + 3];
            }
            s0 += y;
            s1 += y * y;
        }
    }
    __syncthreads();
    red[0][g][c] = s0;
    red[1][g][c] = s1;
    __syncthreads();
    if (t < 64) {
        float a = red[0][0][t] + red[0][1][t] + red[0][2][t] + red[0][3][t];
        float b = red[1][0][t] + red[1][1][t] + red[1][2][t] + red[1][3][t];
        atomicAdd(&stats[t], a);
        atomicAdd(&stats[64 + t], b);
    }
}

// ---------------- final MLP pass + masked max + scatter into NHWC bf16 bev ----------------
__global__ __launch_bounds__(256) void k_pillar(const float* __restrict__ vox,
                                                const int* __restrict__ npts,
                                                const int* __restrict__ coords,
                                                const float* __restrict__ center,
                                                const float* __restrict__ W1,
                                                const float* __restrict__ b1,
                                                const float* __restrict__ ac1,
                                                const float* __restrict__ W2,
                                                const float* __restrict__ b2,
                                                const float* __restrict__ ac2,
                                                ushort* __restrict__ bev) {
    __shared__ float sAug[32][12];
    __shared__ float sH[32][68];
    __shared__ float red[4][64];
    const int t = threadIdx.x;
    const int c = t & 63, g = t >> 6;
    float w1c[10];
#pragma unroll
    for (int k = 0; k < 10; ++k) w1c[k] = W1[k * 64 + c];
    float w2c[64];
#pragma unroll
    for (int k = 0; k < 64; ++k) w2c[k] = W2[k * 64 + c];
    const float b1c = b1[c];
    const float a1 = ac1[c], c1 = ac1[64 + c];
    const float b2c = b2[c];
    const float a2 = ac2[c], c2 = ac2[64 + c];

    for (int pil = blockIdx.x; pil < BATCH * NV; pil += gridDim.x) {
        __syncthreads();
        int np = npts[pil];
        if (np < 0) np = 0;
        if (np > NPTS) np = NPTS;
        if (t < 32) {
            int row = pil * 32 + t;
            float4 v = *(const float4*)(vox + (size_t)row * 4);
            float cx = center[pil * 3 + 0];
            float cy = center[pil * 3 + 1];
            float cz = center[pil * 3 + 2];
            sAug[t][0] = v.x; sAug[t][1] = v.y; sAug[t][2] = v.z; sAug[t][3] = v.w;
            sAug[t][4] = v.x - cx; sAug[t][5] = v.y - cy; sAug[t][6] = v.z - cz;
            sAug[t][7] = v.x - cx; sAug[t][8] = v.y - cy; sAug[t][9] = v.z - cz;
        }
        __syncthreads();
        for (int p = g; p < np; p += 4) {
            float y = b1c;
#pragma unroll
            for (int k = 0; k < 10; ++k) y += sAug[p][k] * w1c[k];
            y = a1 * y + c1;
            sH[p][c] = y > 0.f ? y : 0.f;
        }
        __syncthreads();
        float mx = 0.f;
        for (int p = g; p < np; p += 4) {
            float y = b2c;
#pragma unroll
            for (int k = 0; k < 64; k += 4) {
                float4 h = *(const float4*)&sH[p][k];
                y += h.x * w2c[k] + h.y * w2c[k + 1] + h.z * w2c[k + 2] + h.w * w2c[k + 3];
            }
            y = a2 * y + c2;
            if (y > mx) mx = y;
        }
        red[g][c] = mx;
        __syncthreads();
        if (t < 64) {
            float m0 = red[0][t] > red[1][t] ? red[0][t] : red[1][t];
            float m1 = red[2][t] > red[3][t] ? red[2][t] : red[3][t];
            float m = m0 > m1 ? m0 : m1;
            int x = coords[pil * 3 + 0];
            int y = coords[pil * 3 + 1];
            if (x >= 0 && x < GXX && y >= 0 && y < GYY) {
                int b = pil / NV;
                bev[((size_t)((b * GYY + y) * GXX + x)) * 64 + t] = f2bf(m);
            }
        }
    }
}

// ---------------- weight convert: W[OC][64][3][3] fp32 -> Wb[tap][OC][64 ic] bf16 ----------------
__global__ __launch_bounds__(256) void k_wcvt(const float* __restrict__ src,
                                              ushort* __restrict__ dst, int OC) {
    int idx = blockIdx.x * 256 + threadIdx.x;
    if (idx >= OC * 64 * 9) return;
    int oc = idx / 576;
    int rem = idx - oc * 576;
    int ic = rem / 9;
    int tp = rem - ic * 9;
    dst[((size_t)(tp * OC + oc)) * 64 + ic] = f2bf(src[idx]);
}

// ---------------- MFMA 3x3 SAME conv, NHWC bf16 in, per-tap W dbuf in LDS ----------------
// 16x16 px tile, 4 waves (wave = 4 y-rows, all 64 oc of slab). Single ic pass.
// sX: 18x18 px x (64ch + 8 pad) -> 144B/px, 16B aligned; bank-balanced (group = (pix+kc)&7).
// sW: per-tap [64 oc][64ch + 8 pad], double-buffered; staged from L2 while computing prev tap.
#define ICP 72
#define WPAD 72
__global__ __launch_bounds__(256) void k_conv_mfma(const ushort* __restrict__ in,
                                                   const ushort* __restrict__ Wb,
                                                   const float* __restrict__ bias,
                                                   const float* __restrict__ acIn,
                                                   int useAffine,
                                                   float* __restrict__ outF,   // fp32 NCHW (conv3) or null
                                                   ushort* __restrict__ outH,  // bf16 NHWC (conv1/2) or null
                                                   int N,
                                                   float* __restrict__ stats) {
    __shared__ __align__(16) ushort sX[324 * ICP];        // 46656 B
    __shared__ __align__(16) ushort sW[2][64 * WPAD];     // 18432 B  (total 65088 <= 64KB)
    float* sStat = (float*)&sW[0][0];                     // aliased after compute (2KB)

    const int t = threadIdx.x;
    const int wid = t >> 6, l = t & 63;
    const int hi = l >> 4, lr = l & 15;
    const int tilex = blockIdx.x % 47, tiley = blockIdx.x / 47;
    const int x0 = tilex * 16, y0 = tiley * 16;
    const int ocb = blockIdx.y * 64;
    const int b = blockIdx.z;
    const int c8 = t & 7;        // staging: fixed 16B channel chunk per thread

    // ---- stage X tile once (18x18 px, all 64 ch), affine+relu on load ----
    float aA[8], aC[8];
    if (useAffine) {
#pragma unroll
        for (int i = 0; i < 8; ++i) { aA[i] = acIn[c8 * 8 + i]; aC[i] = acIn[64 + c8 * 8 + i]; }
    }
    for (int idx = t; idx < 324 * 8; idx += 256) {
        int pix = idx >> 3;     // c8 = idx&7 constant per thread (256 % 8 == 0)
        int r = pix / 18, cpx = pix - r * 18;
        int gy = y0 + r - 1, gx = x0 + cpx - 1;
        uint4 v = {0u, 0u, 0u, 0u};
        if (gy >= 0 && gy < GYY && gx >= 0 && gx < GXX) {
            v = *(const uint4*)(in + ((size_t)((b * GYY + gy) * GXX + gx)) * 64 + c8 * 8);
            if (useAffine) {
                uint uu[4] = {v.x, v.y, v.z, v.w};
#pragma unroll
                for (int p = 0; p < 4; ++p) {
                    float f0 = __uint_as_float(uu[p] << 16);
                    float f1 = __uint_as_float(uu[p] & 0xFFFF0000u);
                    f0 = fmaxf(fmaf(aA[p * 2], f0, aC[p * 2]), 0.f);
                    f1 = fmaxf(fmaf(aA[p * 2 + 1], f1, aC[p * 2 + 1]), 0.f);
                    uu[p] = (uint)f2bf(f0) | ((uint)f2bf(f1) << 16);
                }
                v.x = uu[0]; v.y = uu[1]; v.z = uu[2]; v.w = uu[3];
            }
        }
        *(uint4*)(&sX[pix * ICP + c8 * 8]) = v;
    }
    // ---- stage W tap 0 into buf 0 ----
    {
        const ushort* src = Wb + (size_t)(0 * N + ocb) * 64;
#pragma unroll
        for (int k = 0; k < 2; ++k) {
            int idx = t + k * 256;            // 512 chunks: 64 oc x 8
            int oc = idx >> 3, ch = idx & 7;
            uint4 v = *(const uint4*)(src + oc * 64 + ch * 8);
            *(uint4*)(&sW[0][oc * WPAD + ch * 8]) = v;
        }
    }
    __syncthreads();

    f32x4 acc[4][4];
#pragma unroll
    for (int m = 0; m < 4; ++m)
#pragma unroll
        for (int n = 0; n < 4; ++n) acc[m][n] = (f32x4){0.f, 0.f, 0.f, 0.f};

    for (int tp = 0; tp < 9; ++tp) {
        // prefetch next tap's weights into the other buffer
        if (tp < 8) {
            const ushort* src = Wb + (size_t)((tp + 1) * N + ocb) * 64;
            ushort* dst = sW[(tp + 1) & 1];
#pragma unroll
            for (int k = 0; k < 2; ++k) {
                int idx = t + k * 256;
                int oc = idx >> 3, ch = idx & 7;
                uint4 v = *(const uint4*)(src + oc * 64 + ch * 8);
                *(uint4*)(&dst[oc * WPAD + ch * 8]) = v;
            }
        }
        // compute tap tp from buf tp&1
        const ushort* wbuf = sW[tp & 1];
        const int dy = tp / 3 - 1, dx = tp % 3 - 1;
        const int rowb = (wid * 4 + 1 + dy) * 18 + (lr + 1 + dx);
#pragma unroll
        for (int kb = 0; kb < 2; ++kb) {
            const int kc = kb * 4 + hi;
            bfrag8 w[4];
#pragma unroll
            for (int n = 0; n < 4; ++n)
                w[n] = *(const bfrag8*)(&wbuf[(n * 16 + lr) * WPAD + kc * 8]);
#pragma unroll
            for (int m = 0; m < 4; ++m) {
                bfrag8 a = *(const bfrag8*)(&sX[(rowb + m * 18) * ICP + kc * 8]);
#pragma unroll
                for (int n = 0; n < 4; ++n)
                    acc[m][n] = __builtin_amdgcn_mfma_f32_16x16x32_bf16(a, w[n], acc[m][n], 0, 0, 0);
            }
        }
        __syncthreads();
    }

    // ---- epilogue: bias, store pre-BN, stats ----
    float ssum[4] = {0.f, 0.f, 0.f, 0.f}, ssq[4] = {0.f, 0.f, 0.f, 0.f};
    const bool fullx = (x0 + 15 < GXX);
#pragma unroll
    for (int n = 0; n < 4; ++n) {
        const int oc = ocb + n * 16 + lr;
        const float bo = bias[oc];
#pragma unroll
        for (int m = 0; m < 4; ++m) {
            int y = y0 + wid * 4 + m;
            if (y < GYY) {
                float4 v4;
                v4.x = acc[m][n][0] + bo;
                v4.y = acc[m][n][1] + bo;
                v4.z = acc[m][n][2] + bo;
                v4.w = acc[m][n][3] + bo;
                if (outF) {
                    size_t base = ((size_t)(b * N + oc)) * HWSZ + (size_t)y * GXX + x0 + hi * 4;
                    if (fullx) {
                        *(float4*)(outF + base) = v4;
                        ssum[n] += v4.x + v4.y + v4.z + v4.w;
                        ssq[n] += v4.x * v4.x + v4.y * v4.y + v4.z * v4.z + v4.w * v4.w;
                    } else {
                        float vv[4] = {v4.x, v4.y, v4.z, v4.w};
#pragma unroll
                        for (int j = 0; j < 4; ++j) {
                            int x = x0 + hi * 4 + j;
                            if (x < GXX) {
                                outF[base + j] = vv[j];
                                ssum[n] += vv[j];
                                ssq[n] += vv[j] * vv[j];
                            }
                        }
                    }
                } else {
                    float vv[4] = {v4.x, v4.y, v4.z, v4.w};
#pragma unroll
                    for (int j = 0; j < 4; ++j) {
                        int x = x0 + hi * 4 + j;
                        if (x < GXX) {
                            outH[((size_t)((b * GYY + y) * GXX + x)) * 64 + oc] = f2bf(vv[j]);
                            ssum[n] += vv[j];
                            ssq[n] += vv[j] * vv[j];
                        }
                    }
                }
            }
        }
    }
#pragma unroll
    for (int n = 0; n < 4; ++n) {
        ssum[n] += __shfl_xor(ssum[n], 16);
        ssum[n] += __shfl_xor(ssum[n], 32);
        ssq[n] += __shfl_xor(ssq[n], 16);
        ssq[n] += __shfl_xor(ssq[n], 32);
    }
    __syncthreads();   // sW reads fully done (already true), reuse as sStat
    if (l < 16) {
#pragma unroll
        for (int n = 0; n < 4; ++n) {
            sStat[(0 * 4 + wid) * 64 + n * 16 + l] = ssum[n];
            sStat[(1 * 4 + wid) * 64 + n * 16 + l] = ssq[n];
        }
    }
    __syncthreads();
    if (t < 64) {
        float s = sStat[0 * 64 + t] + sStat[1 * 64 + t] + sStat[2 * 64 + t] + sStat[3 * 64 + t];
        float q = sStat[4 * 64 + t] + sStat[5 * 64 + t] + sStat[6 * 64 + t] + sStat[7 * 64 + t];
        atomicAdd(&stats[ocb + t], s);
        atomicAdd(&stats[N + ocb + t], q);
    }
}

// ---------------- in-place BN affine + relu on final output ----------------
__global__ __launch_bounds__(256) void k_bnrelu(float* __restrict__ x,
                                                const float* __restrict__ ac, int nch) {
    const int hw4 = HWSZ / 4;  // 140625
    size_t total = (size_t)BATCH * nch * hw4;
    size_t stride = (size_t)gridDim.x * 256;
    for (size_t idx = (size_t)blockIdx.x * 256 + threadIdx.x; idx < total; idx += stride) {
        int c = (int)((idx / hw4) % nch);
        float a = ac[c], cc = ac[nch + c];
        float4 v = ((float4*)x)[idx];
        v.x = fmaxf(a * v.x + cc, 0.f);
        v.y = fmaxf(a * v.y + cc, 0.f);
        v.z = fmaxf(a * v.z + cc, 0.f);
        v.w = fmaxf(a * v.w + cc, 0.f);
        ((float4*)x)[idx] = v;
    }
}

extern "C" void kernel_launch(void* const* d_in, const int* in_sizes, int n_in,
                              void* d_out, int out_size, void* d_ws, size_t ws_size,
                              hipStream_t stream) {
    const float* voxels = (const float*)d_in[0];
    const int* num_points = (const int*)d_in[1];
    const int* coords = (const int*)d_in[2];
    const float* W1 = (const float*)d_in[3];
    const float* b1 = (const float*)d_in[4];
    const float* g1 = (const float*)d_in[5];
    const float* be1 = (const float*)d_in[6];
    const float* W2 = (const float*)d_in[7];
    const float* b2 = (const float*)d_in[8];
    const float* g2 = (const float*)d_in[9];
    const float* be2 = (const float*)d_in[10];
    const float* Wc1 = (const float*)d_in[11];
    const float* bc1 = (const float*)d_in[12];
    const float* gc1 = (const float*)d_in[13];
    const float* bec1 = (const float*)d_in[14];
    const float* Wc2 = (const float*)d_in[15];
    const float* bc2 = (const float*)d_in[16];
    const float* gc2 = (const float*)d_in[17];
    const float* bec2 = (const float*)d_in[18];
    const float* Wc3 = (const float*)d_in[19];
    const float* bc3 = (const float*)d_in[20];
    const float* gc3 = (const float*)d_in[21];
    const float* bec3 = (const float*)d_in[22];

    float* ws = (float*)d_ws;
    float* center = ws + OFF_CENTER;
    float* stats1 = ws + OFF_STATS1;
    float* ac1 = ws + OFF_AC1;
    float* stats2 = ws + OFF_STATS2;
    float* ac2 = ws + OFF_AC2;
    float* sC1 = ws + OFF_SC1;
    float* acC1 = ws + OFF_ACC1;
    float* sC2 = ws + OFF_SC2;
    float* acC2 = ws + OFF_ACC2;
    float* sC3 = ws + OFF_SC3;
    float* acC3 = ws + OFF_ACC3;
    ushort* Wb1 = (ushort*)(ws + OFF_WB1);
    ushort* Wb2 = (ushort*)(ws + OFF_WB2);
    ushort* Wb3 = (ushort*)(ws + OFF_WB3);
    ushort* bev = (ushort*)(ws + OFF_BEV);   // NHWC bf16
    ushort* mid = (ushort*)(ws + OFF_MID);   // NHWC bf16
    float* outf = (float*)d_out;

    // zero stats block and NHWC bev grid (bf16 zero = 0x0000)
    hipMemsetAsync((char*)d_ws + OFF_STATS1 * sizeof(float), 0,
                   (OFF_STATS_END - OFF_STATS1) * sizeof(float), stream);
    hipMemsetAsync((char*)d_ws + OFF_BEV * sizeof(float), 0,
                   (size_t)BATCH * HWSZ * 64 * sizeof(ushort), stream);

    // weight conversion to bf16 (tap-major)
    k_wcvt<<<144, 256, 0, stream>>>(Wc1, Wb1, 64);
    k_wcvt<<<144, 256, 0, stream>>>(Wc2, Wb2, 64);
    k_wcvt<<<288, 256, 0, stream>>>(Wc3, Wb3, 128);

    // pillar centers
    k_center<<<(BATCH * NV + 255) / 256, 256, 0, stream>>>(voxels, num_points, center);

    // FC1 stats -> affine
    k_fc1_stats<<<1024, 256, 0, stream>>>(voxels, center, W1, b1, stats1);
    k_finalize<<<1, 64, 0, stream>>>(stats1, g1, be1, ac1, 64, 1.0f / NROWS);

    // FC2 stats -> affine
    k_fc2_stats<<<1024, 256, 0, stream>>>(voxels, center, W1, b1, ac1, W2, b2, stats2);
    k_finalize<<<1, 64, 0, stream>>>(stats2, g2, be2, ac2, 64, 1.0f / NROWS);

    // final MLP + max + scatter (NHWC bf16)
    k_pillar<<<4096, 256, 0, stream>>>(voxels, num_points, coords, center,
                                       W1, b1, ac1, W2, b2, ac2, bev);

    const int NT = 47 * 47;
    // conv1: bev(NHWC bf16) -> mid(NHWC bf16 pre-BN), stats
    {
        dim3 grid(NT, 1, BATCH);
        k_conv_mfma<<<grid, 256, 0, stream>>>(bev, Wb1, bc1, nullptr, 0,
                                              nullptr, mid, 64, sC1);
        k_finalize<<<1, 64, 0, stream>>>(sC1, gc1, bec1, acC1, 64, 1.0f / NBHW);
    }
    // conv2: mid (affine+relu on load) -> bev(NHWC bf16 pre-BN), stats
    {
        dim3 grid(NT, 1, BATCH);
        k_conv_mfma<<<grid, 256, 0, stream>>>(mid, Wb2, bc2, acC1, 1,
                                              nullptr, bev, 64, sC2);
        k_finalize<<<1, 64, 0, stream>>>(sC2, gc2, bec2, acC2, 64, 1.0f / NBHW);
    }
    // conv3: bev (affine+relu on load) -> d_out fp32 NCHW pre-BN, stats
    {
        dim3 grid(NT, 2, BATCH);
        k_conv_mfma<<<grid, 256, 0, stream>>>(bev, Wb3, bc3, acC2, 1,
                                              outf, nullptr, 128, sC3);
        k_finalize<<<1, 128, 0, stream>>>(sC3, gc3, bec3, acC3, 128, 1.0f / NBHW);
    }
    // final BN + relu in place on d_out
    k_bnrelu<<<4096, 256, 0, stream>>>(outf, acC3, 128);
}